// Round 1
// baseline (214.950 us; speedup 1.0000x reference)
//
#include <hip/hip_runtime.h>

#define BATCH 2
#define SEQ   384
#define HID   128
#define TABLE (2 * SEQ + 1)   // 769
#define KPB   8               // k-values per block in gather kernel
#define TPB   8               // t-rows per block in precompute

typedef float vfloat4 __attribute__((ext_vector_type(4)));

// ws layout (all f32):
//   U  = 64 * TABLE * HID floats  (25.2 MB)  relu'd combined rows, L2/L3-resident
//   T  = 4  * TABLE * HID floats  (1.57 MB)  per-table GEMM results
//   Wt = 4  * HID * HID floats    (256 KB)   transposed weights

// Kernel 0: Wt[tab][f][h] = W[h][tab*HID + f]   (W row-major [HID, 4*HID])
__global__ void transpose_w(const float* __restrict__ W, float* __restrict__ Wt) {
    const int idx = blockIdx.x * 256 + threadIdx.x;  // tab*16384 + f*128 + h
    const int h   = idx & (HID - 1);
    const int f   = (idx >> 7) & (HID - 1);
    const int tab = idx >> 14;
    Wt[idx] = W[h * (4 * HID) + tab * HID + f];
}

// Kernel 1: T[tab][t][h] = sum_f pe_tab[t][f] * Wt[tab][f][h]  (+ b[h] for tab 0)
__global__ void precompute_tables(const float* __restrict__ pe_ss,
                                  const float* __restrict__ pe_se,
                                  const float* __restrict__ pe_es,
                                  const float* __restrict__ pe_ee,
                                  const float* __restrict__ Wt,
                                  const float* __restrict__ b,
                                  float* __restrict__ T) {
    const int t0  = blockIdx.x * TPB;
    const int tab = blockIdx.y;
    const int h   = threadIdx.x;

    const float* pe = (tab == 0) ? pe_ss : (tab == 1) ? pe_se
                    : (tab == 2) ? pe_es : pe_ee;

    const float* pr[TPB];
#pragma unroll
    for (int r = 0; r < TPB; ++r) {
        int tr = t0 + r; if (tr > TABLE - 1) tr = TABLE - 1;
        pr[r] = pe + (size_t)tr * HID;
    }

    float acc[TPB];
    const float binit = (tab == 0) ? b[h] : 0.0f;
#pragma unroll
    for (int r = 0; r < TPB; ++r) acc[r] = binit;

    const float* wcol = Wt + ((size_t)tab * HID) * HID + h;  // lane-coalesced
#pragma unroll 4
    for (int f = 0; f < HID; ++f) {
        const float wf = wcol[(size_t)f * HID];
#pragma unroll
        for (int r = 0; r < TPB; ++r) acc[r] += pr[r][f] * wf;
    }

#pragma unroll
    for (int r = 0; r < TPB; ++r) {
        const int t = t0 + r;
        if (t < TABLE) T[((size_t)tab * TABLE + t) * HID + h] = acc[r];
    }
}

// Kernel 2: U[(sq*8+sk)][d][h] = relu(T0[d] + T1[d-sk] + T2[d+sq] + T3[d+sq-sk])
// Out-of-range d1/d2/d3 are clamped; those U entries are provably never read
// (actual (d,sq,sk) from valid positions always yield in-range indices).
__global__ void build_u(const float* __restrict__ T, float* __restrict__ U) {
    const int r = threadIdx.x >> 7;          // 0..1
    const int h = threadIdx.x & (HID - 1);
    const int d = blockIdx.x * 2 + r;
    if (d >= TABLE) return;
    const int combo = blockIdx.y;            // sq*8 + sk
    const int sq = combo >> 3;
    const int sk = combo & 7;

    int d1 = d - sk;      if (d1 < 0) d1 = 0;
    int d2 = d + sq;      if (d2 > TABLE - 1) d2 = TABLE - 1;
    int d3 = d + sq - sk; if (d3 < 0) d3 = 0; if (d3 > TABLE - 1) d3 = TABLE - 1;

    const size_t TR = (size_t)TABLE * HID;
    float v = T[(size_t)d  * HID + h]
            + T[TR     + (size_t)d1 * HID + h]
            + T[2 * TR + (size_t)d2 * HID + h]
            + T[3 * TR + (size_t)d3 * HID + h];
    U[((size_t)combo * TABLE + d) * HID + h] = fmaxf(v, 0.0f);
}

// Kernel 3: pure gather-copy. out[b,q,k,:] = U[(sq*8+sk)][ps_q - ps_k + S][:]
// One float4 load (L2/L3-resident U) + one nontemporal float4 store per thread.
__global__ void gather_copy(const int* __restrict__ pos_s,
                            const int* __restrict__ pos_e,
                            const float* __restrict__ U,
                            float* __restrict__ out) {
    const int kk = threadIdx.x >> 5;
    const int h4 = threadIdx.x & 31;
    const int k  = blockIdx.x * KPB + kk;
    const int q  = blockIdx.y;
    const int bb = blockIdx.z;

    const int ps_q = pos_s[bb * SEQ + q];
    const int pe_q = pos_e[bb * SEQ + q];
    const int ps_k = pos_s[bb * SEQ + k];
    const int pe_k = pos_e[bb * SEQ + k];

    const int sq = pe_q - ps_q;              // in [0,7]
    const int sk = pe_k - ps_k;              // in [0,7]
    const int d  = ps_q - ps_k + SEQ;        // in [1,767]

    const size_t row = ((size_t)((sq << 3) | sk) * TABLE + d) * 32;  // float4 units
    const vfloat4 v = ((const vfloat4*)U)[row + h4];

    vfloat4* op = (vfloat4*)out + (((size_t)bb * SEQ + q) * SEQ + k) * 32 + h4;
    __builtin_nontemporal_store(v, op);
}

extern "C" void kernel_launch(void* const* d_in, const int* in_sizes, int n_in,
                              void* d_out, int out_size, void* d_ws, size_t ws_size,
                              hipStream_t stream) {
    const int*   pos_s = (const int*)d_in[0];
    const int*   pos_e = (const int*)d_in[1];
    const float* pe_ss = (const float*)d_in[2];
    const float* pe_se = (const float*)d_in[3];
    const float* pe_es = (const float*)d_in[4];
    const float* pe_ee = (const float*)d_in[5];
    const float* W     = (const float*)d_in[6];
    const float* b     = (const float*)d_in[7];
    float*       out   = (float*)d_out;

    float* U  = (float*)d_ws;                                   // 25,198,592 B
    float* T  = (float*)((char*)d_ws + (size_t)64 * TABLE * HID * sizeof(float));
    float* Wt = (float*)((char*)T    + (size_t)4  * TABLE * HID * sizeof(float));

    transpose_w<<<dim3((4 * HID * HID) / 256), 256, 0, stream>>>(W, Wt);

    precompute_tables<<<dim3((TABLE + TPB - 1) / TPB, 4), HID, 0, stream>>>(
        pe_ss, pe_se, pe_es, pe_ee, Wt, b, T);

    build_u<<<dim3((TABLE + 1) / 2, 64), 256, 0, stream>>>(T, U);

    gather_copy<<<dim3(SEQ / KPB, SEQ, BATCH), 256, 0, stream>>>(
        pos_s, pos_e, U, out);
}

// Round 2
// 195.182 us; speedup vs baseline: 1.1013x; 1.1013x over previous
//
#include <hip/hip_runtime.h>

#define BATCH 2
#define SEQ   384
#define HID   128
#define TABLE (2 * SEQ + 1)   // 769
#define KPB   8               // k-values per block in gather kernel
#define TPB   8               // t-rows per block in precompute

typedef unsigned int   uint32;
typedef unsigned short ushort16;
typedef float  vfloat4 __attribute__((ext_vector_type(4)));
typedef uint32 vuint2  __attribute__((ext_vector_type(2)));

// ws layout:
//   V  (bf16) 8*TABLE*HID  = 1.50 MiB   bf16(T0[d] + T1[d-sk] + b)
//   W2 (bf16) 8*TABLE*HID  = 1.50 MiB   bf16(T2[d] + T3[d-sk])
//   T  (f32)  4*TABLE*HID  = 1.50 MiB   per-table GEMM results (f32 intermediate)
//   Wt (f32)  4*HID*HID    = 256 KiB
// V+W2 = 3.0 MiB -> fully L2-resident per XCD (4 MiB): gather reads at L2 tier.

// bf16 helpers: bf16 is the high half of fp32 — unpack is exact.
__device__ __forceinline__ float blo(uint32 u) { return __uint_as_float(u << 16); }
__device__ __forceinline__ float bhi(uint32 u) { return __uint_as_float(u & 0xFFFF0000u); }
__device__ __forceinline__ ushort16 f2bf_rn(float f) {
    uint32 u = __float_as_uint(f);
    u += 0x7FFFu + ((u >> 16) & 1u);   // round-to-nearest-even
    return (ushort16)(u >> 16);
}

// Kernel 0: Wt[tab][f][h] = W[h][tab*HID + f]   (W row-major [HID, 4*HID])
__global__ void transpose_w(const float* __restrict__ W, float* __restrict__ Wt) {
    const int idx = blockIdx.x * 256 + threadIdx.x;  // tab*16384 + f*128 + h
    const int h   = idx & (HID - 1);
    const int f   = (idx >> 7) & (HID - 1);
    const int tab = idx >> 14;
    Wt[idx] = W[h * (4 * HID) + tab * HID + f];
}

// Kernel 1: T[tab][t][h] = sum_f pe_tab[t][f] * Wt[tab][f][h]  (+ b[h] for tab 0)
__global__ void precompute_tables(const float* __restrict__ pe_ss,
                                  const float* __restrict__ pe_se,
                                  const float* __restrict__ pe_es,
                                  const float* __restrict__ pe_ee,
                                  const float* __restrict__ Wt,
                                  const float* __restrict__ b,
                                  float* __restrict__ T) {
    const int t0  = blockIdx.x * TPB;
    const int tab = blockIdx.y;
    const int h   = threadIdx.x;

    const float* pe = (tab == 0) ? pe_ss : (tab == 1) ? pe_se
                    : (tab == 2) ? pe_es : pe_ee;

    const float* pr[TPB];
#pragma unroll
    for (int r = 0; r < TPB; ++r) {
        int tr = t0 + r; if (tr > TABLE - 1) tr = TABLE - 1;
        pr[r] = pe + (size_t)tr * HID;
    }

    float acc[TPB];
    const float binit = (tab == 0) ? b[h] : 0.0f;  // bias folded into T0 -> V
#pragma unroll
    for (int r = 0; r < TPB; ++r) acc[r] = binit;

    const float* wcol = Wt + ((size_t)tab * HID) * HID + h;  // lane-coalesced
#pragma unroll 4
    for (int f = 0; f < HID; ++f) {
        const float wf = wcol[(size_t)f * HID];
#pragma unroll
        for (int r = 0; r < TPB; ++r) acc[r] += pr[r][f] * wf;
    }

#pragma unroll
    for (int r = 0; r < TPB; ++r) {
        const int t = t0 + r;
        if (t < TABLE) T[((size_t)tab * TABLE + t) * HID + h] = acc[r];
    }
}

// Kernel 2: pairwise combine over sk (span_k in [0,7]):
//   V [sk][d][h] = bf16(T0[d][h] + T1[d-sk][h])   (b already in T0)
//   W2[sk][d][h] = bf16(T2[d][h] + T3[d-sk][h])
// d-sk < 0 clamped; those entries are provably never read (real i_se,i_ee >= 1).
__global__ void build_vw(const float* __restrict__ T,
                         ushort16* __restrict__ V,
                         ushort16* __restrict__ W2) {
    const int h  = threadIdx.x;
    const int d  = blockIdx.x;
    const int sk = blockIdx.y;
    int dm = d - sk; if (dm < 0) dm = 0;

    const size_t TR = (size_t)TABLE * HID;
    const float v = T[(size_t)d * HID + h] + T[TR     + (size_t)dm * HID + h];
    const float w = T[2 * TR + (size_t)d * HID + h] + T[3 * TR + (size_t)dm * HID + h];

    const size_t o = ((size_t)sk * TABLE + d) * HID + h;
    V[o]  = f2bf_rn(v);
    W2[o] = f2bf_rn(w);
}

// Kernel 3: out[b,q,k,h] = relu(V[sk][d][h] + W2[sk][d+sq][h])
//   sk = pe_k-ps_k, sq = pe_q-ps_q, d = ps_q-ps_k+SEQ
// 2 L2-resident 8-byte loads + 1 nontemporal float4 store per thread.
__global__ void gather_fuse2(const int* __restrict__ pos_s,
                             const int* __restrict__ pos_e,
                             const ushort16* __restrict__ V,
                             const ushort16* __restrict__ W2,
                             float* __restrict__ out) {
    const int kk = threadIdx.x >> 5;
    const int h4 = threadIdx.x & 31;
    const int k  = blockIdx.x * KPB + kk;
    const int q  = blockIdx.y;
    const int bb = blockIdx.z;

    const int ps_q = pos_s[bb * SEQ + q];
    const int pe_q = pos_e[bb * SEQ + q];
    const int ps_k = pos_s[bb * SEQ + k];
    const int pe_k = pos_e[bb * SEQ + k];

    const int sq = pe_q - ps_q;              // in [0,7]
    const int sk = pe_k - ps_k;              // in [0,7]
    const int d  = ps_q - ps_k + SEQ;        // in [1,767]

    // one table row = 128 bf16 = 32 vuint2
    const vuint2* Vv = (const vuint2*)V;
    const vuint2* Wv = (const vuint2*)W2;

    const vuint2 a = Vv[((size_t)sk * TABLE + d     ) * 32 + h4];
    const vuint2 c = Wv[((size_t)sk * TABLE + d + sq) * 32 + h4];

    vfloat4 r;
    r.x = fmaxf(blo(a.x) + blo(c.x), 0.0f);
    r.y = fmaxf(bhi(a.x) + bhi(c.x), 0.0f);
    r.z = fmaxf(blo(a.y) + blo(c.y), 0.0f);
    r.w = fmaxf(bhi(a.y) + bhi(c.y), 0.0f);

    vfloat4* op = (vfloat4*)out + (((size_t)bb * SEQ + q) * SEQ + k) * 32 + h4;
    __builtin_nontemporal_store(r, op);
}

extern "C" void kernel_launch(void* const* d_in, const int* in_sizes, int n_in,
                              void* d_out, int out_size, void* d_ws, size_t ws_size,
                              hipStream_t stream) {
    const int*   pos_s = (const int*)d_in[0];
    const int*   pos_e = (const int*)d_in[1];
    const float* pe_ss = (const float*)d_in[2];
    const float* pe_se = (const float*)d_in[3];
    const float* pe_es = (const float*)d_in[4];
    const float* pe_ee = (const float*)d_in[5];
    const float* W     = (const float*)d_in[6];
    const float* b     = (const float*)d_in[7];
    float*       out   = (float*)d_out;

    const size_t VW_ELEMS = (size_t)8 * TABLE * HID;         // per table
    ushort16* V  = (ushort16*)d_ws;
    ushort16* W2 = V + VW_ELEMS;
    float*    T  = (float*)(W2 + VW_ELEMS);
    float*    Wt = T + (size_t)4 * TABLE * HID;

    transpose_w<<<dim3((4 * HID * HID) / 256), 256, 0, stream>>>(W, Wt);

    precompute_tables<<<dim3((TABLE + TPB - 1) / TPB, 4), HID, 0, stream>>>(
        pe_ss, pe_se, pe_es, pe_ee, Wt, b, T);

    build_vw<<<dim3(TABLE, 8), HID, 0, stream>>>(T, V, W2);

    gather_fuse2<<<dim3(SEQ / KPB, SEQ, BATCH), 256, 0, stream>>>(
        pos_s, pos_e, V, W2, out);
}